// Round 3
// baseline (545.108 us; speedup 1.0000x reference)
//
#include <hip/hip_runtime.h>
#include <hip/hip_cooperative_groups.h>

namespace cg = cooperative_groups;

#define FEAT 128

typedef __attribute__((ext_vector_type(8))) short short8;
typedef __attribute__((ext_vector_type(4))) float floatx4;

// bf16 helpers (manual, RNE) — finite data only.
__device__ __forceinline__ unsigned short f2bf(float f) {
    unsigned int u = __float_as_uint(f);
    u += 0x7fffu + ((u >> 16) & 1u);
    return (unsigned short)(u >> 16);
}
__device__ __forceinline__ float bf_lo(unsigned int u) { return __uint_as_float(u << 16); }
__device__ __forceinline__ float bf_hi(unsigned int u) { return __uint_as_float(u & 0xffff0000u); }

// ===========================================================================
// ONE cooperative prep kernel replacing memset + convert_hist + scan_chunk +
// add_base + permute + prep_w (7 graph nodes -> 1). Phases separated by
// grid.sync(); 512 blocks x 256 thr = 2 blocks/CU, trivially co-resident.
// x is no longer converted to bf16 at all — layer 1 gathers fp32 directly.
// ===========================================================================
__global__ __launch_bounds__(256) void prep_all(
        const int* __restrict__ src, const int* __restrict__ dst,
        int* __restrict__ counts, int* __restrict__ offsets,
        int* __restrict__ cursor, int* __restrict__ blocksums,
        int* __restrict__ sorted_src,
        const float* __restrict__ W1, const float* __restrict__ W2,
        unsigned short* __restrict__ bfW1, unsigned short* __restrict__ bfW2,
        int N, int E) {
    cg::grid_group grid = cg::this_grid();
    const int t = threadIdx.x;
    const int gsz = gridDim.x * 256;
    const int gtid = blockIdx.x * 256 + t;

    // ---- phase 0: zero counts; last two blocks also repack W1/W2 into
    //      MFMA fragment order:
    //      bfW[((kc*8+ct)*64+lane)*8+j] = bf16(W[kc*32+(lane>>4)*8+j][ct*16+(lane&15)])
    for (int i = gtid; i < N; i += gsz) counts[i] = 0;
    if (blockIdx.x >= gridDim.x - 2) {
        const int wsel = blockIdx.x - (gridDim.x - 2);
        const float* W = wsel ? W2 : W1;
        unsigned short* bfW = wsel ? bfW2 : bfW1;
#pragma unroll
        for (int it = 0; it < 8; it++) {
            const int idx = it * 256 + t;
            const int kc = idx >> 9;
            const int ct = (idx >> 6) & 7;
            const int lane = idx & 63;
            const int quad = lane >> 4;
            const int n = ct * 16 + (lane & 15);
            unsigned short frag[8];
#pragma unroll
            for (int j = 0; j < 8; j++)
                frag[j] = f2bf(W[(kc * 32 + quad * 8 + j) * FEAT + n]);
            *(uint4*)&bfW[(long)idx * 8] = *(uint4*)frag;
        }
    }
    grid.sync();

    // ---- phase 1: dst histogram
    for (int e = gtid; e < E; e += gsz) atomicAdd(&counts[dst[e]], 1);
    grid.sync();

    // ---- phase 2: per-chunk exclusive scan (1024 nodes/block, blocks 0..NB-1)
    const int NB = (N + 1023) >> 10;
    __shared__ int ws[4];
    if (blockIdx.x < NB) {
        const int base = blockIdx.x * 1024 + t * 4;
        int c0 = (base + 0 < N) ? counts[base + 0] : 0;
        int c1 = (base + 1 < N) ? counts[base + 1] : 0;
        int c2 = (base + 2 < N) ? counts[base + 2] : 0;
        int c3 = (base + 3 < N) ? counts[base + 3] : 0;
        const int sum = c0 + c1 + c2 + c3;
        const int lane = t & 63, wv = t >> 6;
        int v = sum;
#pragma unroll
        for (int off = 1; off < 64; off <<= 1) {
            int n = __shfl_up(v, off);
            if (lane >= off) v += n;
        }
        if (lane == 63) ws[wv] = v;
        __syncthreads();
        int wp = 0;
        for (int w = 0; w < wv; w++) wp += ws[w];
        const int excl = wp + v - sum;
        if (base + 0 < N) offsets[base + 0] = excl;
        if (base + 1 < N) offsets[base + 1] = excl + c0;
        if (base + 2 < N) offsets[base + 2] = excl + c0 + c1;
        if (base + 3 < N) offsets[base + 3] = excl + c0 + c1 + c2;
        if (t == 255) blocksums[blockIdx.x] = wp + v;
    }
    grid.sync();

    // ---- phase 3: block 0 turns blocksums[0..NB) into its exclusive prefix
    if (blockIdx.x == 0) {
        int val = (t < NB) ? blocksums[t] : 0;
        int v = val;
        const int lane = t & 63, wv = t >> 6;
#pragma unroll
        for (int off = 1; off < 64; off <<= 1) {
            int n = __shfl_up(v, off);
            if (lane >= off) v += n;
        }
        if (lane == 63) ws[wv] = v;
        __syncthreads();
        int wp = 0;
        for (int w = 0; w < wv; w++) wp += ws[w];
        if (t < NB) blocksums[t] = wp + v - val;   // exclusive
    }
    grid.sync();

    // ---- phase 4: add chunk base; duplicate into cursor; cap offsets[N]
    for (int i = gtid; i < N; i += gsz) {
        const int off = offsets[i] + blocksums[i >> 10];
        offsets[i] = off;
        cursor[i] = off;
    }
    if (gtid == 0) offsets[N] = E;
    grid.sync();

    // ---- phase 5: stable-ish permute of src by dst bucket
    for (int e = gtid; e < E; e += gsz) {
        const int pos = atomicAdd(&cursor[dst[e]], 1);
        sorted_src[pos] = src[e];
    }
}

// ===========================================================================
// FUSED gather + MFMA GEMM — zero LDS, no barriers, 128-THREAD blocks:
//   out_rows[i] = (sum_{e in CSR(i)} h[sorted_src[e]]) @ W + bias  [opt ReLU]
// IN_BF16=false: gather fp32 rows (512 B) — used for layer 1 directly on x,
// eliminating the x->bf16 convert pass. IN_BF16=true: bf16 rows (256 B).
// Lane (l15, quad) gathers node (blk*32 + wave*16 + l15), feature chunk
// kc*32+quad*8..+8 — the fp32 accumulator IS the MFMA A-fragment.
// ===========================================================================
__device__ __forceinline__ void acc_row_bf(float acc[4][8], const uint4 u[4]) {
#pragma unroll
    for (int kc = 0; kc < 4; kc++) {
        acc[kc][0] += bf_lo(u[kc].x); acc[kc][1] += bf_hi(u[kc].x);
        acc[kc][2] += bf_lo(u[kc].y); acc[kc][3] += bf_hi(u[kc].y);
        acc[kc][4] += bf_lo(u[kc].z); acc[kc][5] += bf_hi(u[kc].z);
        acc[kc][6] += bf_lo(u[kc].w); acc[kc][7] += bf_hi(u[kc].w);
    }
}
__device__ __forceinline__ void acc_row_f32(float acc[4][8], const float4 f[8]) {
#pragma unroll
    for (int kc = 0; kc < 4; kc++) {
        acc[kc][0] += f[kc * 2].x; acc[kc][1] += f[kc * 2].y;
        acc[kc][2] += f[kc * 2].z; acc[kc][3] += f[kc * 2].w;
        acc[kc][4] += f[kc * 2 + 1].x; acc[kc][5] += f[kc * 2 + 1].y;
        acc[kc][6] += f[kc * 2 + 1].z; acc[kc][7] += f[kc * 2 + 1].w;
    }
}

template <bool RELU, bool OUT_BF16, bool IN_BF16>
__global__ __launch_bounds__(128, 4) void gather_gemm(const void* __restrict__ hvoid,
                                                      const int* __restrict__ offsets,
                                                      const int* __restrict__ sorted_src,
                                                      const unsigned short* __restrict__ bfW,
                                                      const float* __restrict__ bias,
                                                      void* __restrict__ out, int N) {
    const int t = threadIdx.x;
    const int wave = t >> 6;
    const int lane = t & 63;
    const int quad = lane >> 4;
    const int l15 = lane & 15;
    const int node = blockIdx.x * 32 + wave * 16 + l15;

    int start = 0, end = 0;
    if (node < N) { start = offsets[node]; end = offsets[node + 1]; }

    const uint4* hb = (const uint4*)hvoid;     // bf16: 16 uint4 per row
    const float4* hf = (const float4*)hvoid;   // fp32: 32 float4 per row
    float acc[4][8];
#pragma unroll
    for (int kc = 0; kc < 4; kc++)
#pragma unroll
        for (int j = 0; j < 8; j++) acc[kc][j] = 0.f;

    // ---- gather phase (lane holds edge indices quad*2, quad*2+1 of node l15;
    //      all 4 quads of a column share start/end so shfl providers are in
    //      lockstep with their readers) ----
    int e0 = start + quad * 2;
    int s0 = (e0 < end) ? sorted_src[e0] : 0;
    int s1 = (e0 + 1 < end) ? sorted_src[e0 + 1] : 0;

    for (int eb = start; eb < end; eb += 8) {
        const int ne = eb + 8 + quad * 2;
        const int ns0 = (ne < end) ? sorted_src[ne] : 0;
        const int ns1 = (ne + 1 < end) ? sorted_src[ne + 1] : 0;

        const int cnt = min(8, end - eb);
#pragma unroll
        for (int jp = 0; jp < 4; jp++) {
            const int j0 = jp * 2;
            if (j0 >= cnt) break;
            const int sl = jp * 16 + l15;
            const int sA = __shfl(s0, sl);            // edge eb+2*jp
            const int sB = __shfl(s1, sl);            // edge eb+2*jp+1 (0 if OOR)
            if constexpr (IN_BF16) {
                const long rA = (long)sA * 16;
                const long rB = (long)sB * 16;
                uint4 uA[4], uB[4];
#pragma unroll
                for (int kc = 0; kc < 4; kc++) uA[kc] = hb[rA + kc * 4 + quad];
#pragma unroll
                for (int kc = 0; kc < 4; kc++) uB[kc] = hb[rB + kc * 4 + quad];
                acc_row_bf(acc, uA);
                if (j0 + 1 < cnt) acc_row_bf(acc, uB);
            } else {
                const long rA = (long)sA * 32;
                const long rB = (long)sB * 32;
                float4 fA[8], fB[8];
#pragma unroll
                for (int kc = 0; kc < 4; kc++) {
                    fA[kc * 2]     = hf[rA + kc * 8 + quad * 2];
                    fA[kc * 2 + 1] = hf[rA + kc * 8 + quad * 2 + 1];
                }
#pragma unroll
                for (int kc = 0; kc < 4; kc++) {
                    fB[kc * 2]     = hf[rB + kc * 8 + quad * 2];
                    fB[kc * 2 + 1] = hf[rB + kc * 8 + quad * 2 + 1];
                }
                acc_row_f32(acc, fA);
                if (j0 + 1 < cnt) acc_row_f32(acc, fB);
            }
        }
        s0 = ns0; s1 = ns1;
    }

    // acc -> A fragments (register-only; layout already matches).
    short8 afrag[4];
#pragma unroll
    for (int kc = 0; kc < 4; kc++) {
        unsigned short fr[8];
#pragma unroll
        for (int j = 0; j < 8; j++) fr[j] = f2bf(acc[kc][j]);
        afrag[kc] = *(short8*)fr;
    }

    // ---- MFMA phase: B-frags straight from global (L1/L2-hot 32 KB) ----
    floatx4 cacc[8];
#pragma unroll
    for (int ct = 0; ct < 8; ct++) cacc[ct] = (floatx4){0.f, 0.f, 0.f, 0.f};
#pragma unroll
    for (int kc = 0; kc < 4; kc++) {
#pragma unroll
        for (int ct = 0; ct < 8; ct++) {
            const short8 b = *(const short8*)&bfW[((kc * 8 + ct) * 64 + lane) * 8];
            cacc[ct] = __builtin_amdgcn_mfma_f32_16x16x32_bf16(afrag[kc], b, cacc[ct], 0, 0, 0);
        }
    }

    // ---- epilogue: C/D layout col=ct*16+l15, row=quad*4+r, direct stores.
#pragma unroll
    for (int ct = 0; ct < 8; ct++) {
        const int col = ct * 16 + l15;
        const float bv = bias[col];
#pragma unroll
        for (int r = 0; r < 4; r++) {
            const int row = blockIdx.x * 32 + wave * 16 + quad * 4 + r;
            if (row < N) {
                float v = cacc[ct][r] + bv;
                if (RELU) v = fmaxf(v, 0.f);
                if (OUT_BF16)
                    ((unsigned short*)out)[(long)row * FEAT + col] = f2bf(v);
                else
                    ((float*)out)[(long)row * FEAT + col] = v;
            }
        }
    }
}

// ===========================================================================
// Pipeline (3 graph nodes):
//   prep_all (cooperative): counts=0/W-prep | hist | scan | scan2 | base | permute
//   h1b = gather_gemm<relu, bf16-out, fp32-in>(x,  W1, b1)
//   out = gather_gemm<    , fp32-out, bf16-in>(h1b, W2, b2)
// Linearity: segment_sum((hW)[src]) == (segment_sum h[src]) @ W.
// ===========================================================================
extern "C" void kernel_launch(void* const* d_in, const int* in_sizes, int n_in,
                              void* d_out, int out_size, void* d_ws, size_t ws_size,
                              hipStream_t stream) {
    const float* x  = (const float*)d_in[0];
    const int*   ei = (const int*)d_in[1];
    const float* W1 = (const float*)d_in[2];
    const float* b1 = (const float*)d_in[3];
    const float* W2 = (const float*)d_in[4];
    const float* b2 = (const float*)d_in[5];
    float* out = (float*)d_out;

    int N = in_sizes[0] / FEAT;
    int E = in_sizes[1] / 2;
    const int* src = ei;
    const int* dst = ei + E;

    // Workspace carve-up (~30 MB).
    unsigned short* h1b  = (unsigned short*)d_ws;            // N*128 bf16
    unsigned short* bfW1 = h1b + (size_t)N * FEAT;           // 16384
    unsigned short* bfW2 = bfW1 + 16384;                     // 16384
    int* counts    = (int*)(bfW2 + 16384);                   // [N]
    int* offsets   = counts + N;                             // [N+1]
    int* cursor    = offsets + N + 1;                        // [N]
    int* blocksums = cursor + N;                             // [<=128]
    int* sorted_src = blocksums + 128;                       // [E]

    // ---- single cooperative prep kernel ----
    {
        const int* srcA = src; const int* dstA = dst;
        int* cA = counts; int* oA = offsets; int* cuA = cursor;
        int* bsA = blocksums; int* ssA = sorted_src;
        const float* w1A = W1; const float* w2A = W2;
        unsigned short* bw1A = bfW1; unsigned short* bw2A = bfW2;
        void* args[] = { &srcA, &dstA, &cA, &oA, &cuA, &bsA, &ssA,
                         &w1A, &w2A, &bw1A, &bw2A, &N, &E };
        hipLaunchCooperativeKernel(reinterpret_cast<void*>(prep_all),
                                   dim3(512), dim3(256), args, 0, stream);
    }

    const int fused_blocks = (N + 31) / 32;

    // ---- Layer 1 (fp32 in, bf16 out) / Layer 2 (bf16 in, fp32 out) ----
    gather_gemm<true, true, false><<<fused_blocks, 128, 0, stream>>>(
        x, offsets, sorted_src, bfW1, b1, h1b, N);
    gather_gemm<false, false, true><<<fused_blocks, 128, 0, stream>>>(
        h1b, offsets, sorted_src, bfW2, b2, out, N);
}

// Round 4
// 257.974 us; speedup vs baseline: 2.1130x; 2.1130x over previous
//
#include <hip/hip_runtime.h>

#define FEAT 128

typedef __attribute__((ext_vector_type(8))) short short8;
typedef __attribute__((ext_vector_type(4))) float floatx4;

// bf16 helpers (manual, RNE) — finite data only.
__device__ __forceinline__ unsigned short f2bf(float f) {
    unsigned int u = __float_as_uint(f);
    u += 0x7fffu + ((u >> 16) & 1u);
    return (unsigned short)(u >> 16);
}
__device__ __forceinline__ float bf_lo(unsigned int u) { return __uint_as_float(u << 16); }
__device__ __forceinline__ float bf_hi(unsigned int u) { return __uint_as_float(u & 0xffff0000u); }
__device__ __forceinline__ unsigned int pack2(float a, float b) {
    return (unsigned int)f2bf(a) | ((unsigned int)f2bf(b) << 16);
}

// ===========================================================================
// Fused convert + histogram + W-prep:
//  blocks [0, chB): stream x -> bf16 while issuing dst-histogram atomics
//  blocks chB, chB+1: repack W1/W2 into MFMA fragment order.
// ===========================================================================
__global__ __launch_bounds__(256) void convert_hist_prep(
        const float* __restrict__ x, unsigned short* __restrict__ xb, long n4,
        const int* __restrict__ dst, int* __restrict__ counts, int E,
        const float* __restrict__ W1, const float* __restrict__ W2,
        unsigned short* __restrict__ bfW1, unsigned short* __restrict__ bfW2,
        int chB) {
    const int t = threadIdx.x;
    if (blockIdx.x >= chB) {
        // bfW[((kc*8+ct)*64+lane)*8+j] = bf16(W[kc*32+(lane>>4)*8+j][ct*16+(lane&15)])
        const int wsel = blockIdx.x - chB;
        const float* W = wsel ? W2 : W1;
        unsigned short* bfW = wsel ? bfW2 : bfW1;
#pragma unroll
        for (int it = 0; it < 8; it++) {
            const int idx = it * 256 + t;
            const int kc = idx >> 9;
            const int ct = (idx >> 6) & 7;
            const int lane = idx & 63;
            const int quad = lane >> 4;
            const int n = ct * 16 + (lane & 15);
            unsigned short frag[8];
#pragma unroll
            for (int j = 0; j < 8; j++)
                frag[j] = f2bf(W[(kc * 32 + quad * 8 + j) * FEAT + n]);
            *(uint4*)&bfW[(long)idx * 8] = *(uint4*)frag;
        }
        return;
    }
    const long i = (long)blockIdx.x * 256 + t;
    if (i < E) atomicAdd(&counts[dst[i]], 1);
    if (i < n4) {
        const float4 v = *(const float4*)&x[i * 4];
        uint2 p;
        p.x = pack2(v.x, v.y);
        p.y = pack2(v.z, v.w);
        *(uint2*)&xb[i * 4] = p;
    }
}

// ===========================================================================
// Exclusive scan level 1: 256 threads x 4 elems = 1024-chunk per block.
// ===========================================================================
__global__ __launch_bounds__(256) void scan_chunk(const int* __restrict__ counts,
                                                  int* __restrict__ offsets,
                                                  int* __restrict__ blocksums, int N) {
    const int t = threadIdx.x;
    const int base = blockIdx.x * 1024 + t * 4;
    int c0 = (base + 0 < N) ? counts[base + 0] : 0;
    int c1 = (base + 1 < N) ? counts[base + 1] : 0;
    int c2 = (base + 2 < N) ? counts[base + 2] : 0;
    int c3 = (base + 3 < N) ? counts[base + 3] : 0;
    const int sum = c0 + c1 + c2 + c3;

    const int lane = t & 63, wv = t >> 6;
    int v = sum;
#pragma unroll
    for (int off = 1; off < 64; off <<= 1) {
        int n = __shfl_up(v, off);
        if (lane >= off) v += n;
    }
    __shared__ int ws[4];
    if (lane == 63) ws[wv] = v;
    __syncthreads();
    int wp = 0;
    for (int w = 0; w < wv; w++) wp += ws[w];
    int excl = wp + v - sum;

    if (base + 0 < N) offsets[base + 0] = excl;
    if (base + 1 < N) offsets[base + 1] = excl + c0;
    if (base + 2 < N) offsets[base + 2] = excl + c0 + c1;
    if (base + 3 < N) offsets[base + 3] = excl + c0 + c1 + c2;
    if (t == 255) blocksums[blockIdx.x] = wp + v;
}

// ===========================================================================
// Scan level 2 fused into add_base: each block re-derives prefix of
// blocksums[0..c) with wave 0, adds it, duplicates into cursor, caps
// offsets[N] = E.
// ===========================================================================
__global__ __launch_bounds__(256) void add_base(int* __restrict__ offsets,
                                                int* __restrict__ cursor,
                                                const int* __restrict__ blocksums,
                                                int N, int E) {
    __shared__ int sbase;
    const int c = blockIdx.x >> 2;       // this block's chunk id
    const int t = threadIdx.x;
    if (t < 64) {
        int s = 0;
        for (int j = t; j < c; j += 64) s += blocksums[j];
#pragma unroll
        for (int off = 32; off; off >>= 1) s += __shfl_down(s, off);
        if (t == 0) sbase = s;
    }
    __syncthreads();
    const int base = sbase;
    const int i = blockIdx.x * 256 + t;
    if (i < N) {
        const int off = offsets[i] + base;
        offsets[i] = off;
        cursor[i] = off;
    }
    if (i == 0) offsets[N] = E;
}

__global__ __launch_bounds__(256) void permute_kernel(const int* __restrict__ src,
                                                      const int* __restrict__ dst,
                                                      int* __restrict__ cursor,
                                                      int* __restrict__ sorted_src, int E) {
    const int e = blockIdx.x * 256 + threadIdx.x;
    if (e < E) {
        const int pos = atomicAdd(&cursor[dst[e]], 1);
        sorted_src[pos] = src[e];
    }
}

// ===========================================================================
// FUSED gather + MFMA GEMM — zero LDS, no barriers, 128-THREAD blocks:
//   out_rows[i] = (sum_{e in CSR(i)} h[sorted_src[e]]) @ W + bias  [opt ReLU]
//
// Round-4 change: amdgpu_waves_per_eu(4,4) pins the scheduler's occupancy
// target to 4 waves/EU (VGPR budget 128) — round 2 showed __launch_bounds__
// min-waves alone lets the pressure-aware scheduler re-serialize loads at
// 48 VGPR. Inner loop now batches FOUR edges: 16 independent uint4 loads
// (64 VGPRs of payload) issued before any accumulate — 4x the per-wave MLP.
// OOR edges load row 0 (indices pre-forced to 0); only accumulates masked.
// ===========================================================================
__device__ __forceinline__ void acc_row_bf(float acc[4][8], const uint4 u[4]) {
#pragma unroll
    for (int kc = 0; kc < 4; kc++) {
        acc[kc][0] += bf_lo(u[kc].x); acc[kc][1] += bf_hi(u[kc].x);
        acc[kc][2] += bf_lo(u[kc].y); acc[kc][3] += bf_hi(u[kc].y);
        acc[kc][4] += bf_lo(u[kc].z); acc[kc][5] += bf_hi(u[kc].z);
        acc[kc][6] += bf_lo(u[kc].w); acc[kc][7] += bf_hi(u[kc].w);
    }
}

template <bool RELU, bool OUT_BF16>
__global__ __attribute__((amdgpu_flat_work_group_size(128, 128),
                          amdgpu_waves_per_eu(4, 4)))
void gather_gemm(const unsigned short* __restrict__ h,
                 const int* __restrict__ offsets,
                 const int* __restrict__ sorted_src,
                 const unsigned short* __restrict__ bfW,
                 const float* __restrict__ bias,
                 void* __restrict__ out, int N) {
    const int t = threadIdx.x;
    const int wave = t >> 6;
    const int lane = t & 63;
    const int quad = lane >> 4;
    const int l15 = lane & 15;
    const int node = blockIdx.x * 32 + wave * 16 + l15;

    int start = 0, end = 0;
    if (node < N) { start = offsets[node]; end = offsets[node + 1]; }

    const uint4* hb = (const uint4*)h;   // 16 uint4 per 128-feat row
    float acc[4][8];
#pragma unroll
    for (int kc = 0; kc < 4; kc++)
#pragma unroll
        for (int j = 0; j < 8; j++) acc[kc][j] = 0.f;

    // ---- gather phase ----
    // Lane (quad,l15) holds edge indices start+quad*2, +quad*2+1 of node l15.
    // All 4 quads of a column share start/end, so shfl providers are in
    // lockstep with their readers.
    int e0 = start + quad * 2;
    int s0 = (e0 < end) ? sorted_src[e0] : 0;
    int s1 = (e0 + 1 < end) ? sorted_src[e0 + 1] : 0;

    for (int eb = start; eb < end; eb += 8) {
        // Prefetch next batch's indices (hides index-load latency).
        const int ne = eb + 8 + quad * 2;
        const int ns0 = (ne < end) ? sorted_src[ne] : 0;
        const int ns1 = (ne + 1 < end) ? sorted_src[ne + 1] : 0;

        const int cnt = min(8, end - eb);
        // Two halves of 4 edges; each half = 16 loads in flight, then acc.
#pragma unroll
        for (int hh = 0; hh < 2; hh++) {
            if (hh * 4 >= cnt) break;            // divergent (uniform per column)
            int sv[4];
#pragma unroll
            for (int je = 0; je < 4; je++) {
                const int e = hh * 4 + je;
                const int sl = (e >> 1) * 16 + l15;
                sv[je] = __shfl((e & 1) ? s1 : s0, sl);   // 0 if OOR
            }
            uint4 u[4][4];
#pragma unroll
            for (int je = 0; je < 4; je++) {
                const long rb = (long)sv[je] * 16;
#pragma unroll
                for (int kc = 0; kc < 4; kc++) u[je][kc] = hb[rb + kc * 4 + quad];
            }
#pragma unroll
            for (int je = 0; je < 4; je++) {
                if (hh * 4 + je < cnt) acc_row_bf(acc, u[je]);
            }
        }
        s0 = ns0; s1 = ns1;
    }

    // acc -> A fragments (register-only; layout already matches).
    short8 afrag[4];
#pragma unroll
    for (int kc = 0; kc < 4; kc++) {
        unsigned short fr[8];
#pragma unroll
        for (int j = 0; j < 8; j++) fr[j] = f2bf(acc[kc][j]);
        afrag[kc] = *(short8*)fr;
    }

    // ---- MFMA phase: B-frags straight from global (L1/L2-hot 32 KB) ----
    floatx4 cacc[8];
#pragma unroll
    for (int ct = 0; ct < 8; ct++) cacc[ct] = (floatx4){0.f, 0.f, 0.f, 0.f};
#pragma unroll
    for (int kc = 0; kc < 4; kc++) {
#pragma unroll
        for (int ct = 0; ct < 8; ct++) {
            const short8 b = *(const short8*)&bfW[((kc * 8 + ct) * 64 + lane) * 8];
            cacc[ct] = __builtin_amdgcn_mfma_f32_16x16x32_bf16(afrag[kc], b, cacc[ct], 0, 0, 0);
        }
    }

    // ---- epilogue: C/D layout col=ct*16+l15, row=quad*4+r, direct stores.
#pragma unroll
    for (int ct = 0; ct < 8; ct++) {
        const int col = ct * 16 + l15;
        const float bv = bias[col];
#pragma unroll
        for (int r = 0; r < 4; r++) {
            const int row = blockIdx.x * 32 + wave * 16 + quad * 4 + r;
            if (row < N) {
                float v = cacc[ct][r] + bv;
                if (RELU) v = fmaxf(v, 0.f);
                if (OUT_BF16)
                    ((unsigned short*)out)[(long)row * FEAT + col] = f2bf(v);
                else
                    ((float*)out)[(long)row * FEAT + col] = v;
            }
        }
    }
}

// ===========================================================================
// Pipeline (bf16 payloads, fp32 accumulation):
//   counts=0; convert+hist+prep_w; scan; add_base(+scan2); permute
//   h1b = fused_gather_gemm(xb, W1, b1, relu) -> bf16
//   out = fused_gather_gemm(h1b, W2, b2)      -> fp32
// Linearity: segment_sum((hW)[src]) == (segment_sum h[src]) @ W.
// ===========================================================================
extern "C" void kernel_launch(void* const* d_in, const int* in_sizes, int n_in,
                              void* d_out, int out_size, void* d_ws, size_t ws_size,
                              hipStream_t stream) {
    const float* x  = (const float*)d_in[0];
    const int*   ei = (const int*)d_in[1];
    const float* W1 = (const float*)d_in[2];
    const float* b1 = (const float*)d_in[3];
    const float* W2 = (const float*)d_in[4];
    const float* b2 = (const float*)d_in[5];
    float* out = (float*)d_out;

    const int N = in_sizes[0] / FEAT;
    const int E = in_sizes[1] / 2;
    const int* src = ei;
    const int* dst = ei + E;

    // Workspace carve-up (~55 MB).
    unsigned short* xb   = (unsigned short*)d_ws;            // N*128 bf16
    unsigned short* h1b  = xb + (size_t)N * FEAT;            // N*128 bf16
    unsigned short* bfW1 = h1b + (size_t)N * FEAT;           // 16384
    unsigned short* bfW2 = bfW1 + 16384;                     // 16384
    int* counts    = (int*)(bfW2 + 16384);                   // [N]
    int* offsets   = counts + N;                             // [N+1]
    int* cursor    = offsets + N + 1;                        // [N]
    int* blocksums = cursor + N;                             // [<=128]
    int* sorted_src = blocksums + 128;                       // [E]

    const int NB = (N + 1023) / 1024;
    const int eb = (E + 255) / 256;
    const int nb = (N + 255) / 256;
    const long n4 = (long)N * FEAT / 4;
    const int chB = (int)((n4 + 255) / 256);

    // ---- CSR build + bf16 prep (+ concurrent W repack) ----
    hipMemsetAsync(counts, 0, (size_t)N * sizeof(int), stream);
    convert_hist_prep<<<chB + 2, 256, 0, stream>>>(x, xb, n4, dst, counts, E,
                                                   W1, W2, bfW1, bfW2, chB);
    scan_chunk<<<NB, 256, 0, stream>>>(counts, offsets, blocksums, N);
    add_base<<<nb, 256, 0, stream>>>(offsets, cursor, blocksums, N, E);
    permute_kernel<<<eb, 256, 0, stream>>>(src, dst, cursor, sorted_src, E);

    const int fused_blocks = (N + 31) / 32;

    // ---- Layer 1 (bf16 out) / Layer 2 (fp32 out) ----
    gather_gemm<true, true><<<fused_blocks, 128, 0, stream>>>(
        xb, offsets, sorted_src, bfW1, b1, h1b, N);
    gather_gemm<false, false><<<fused_blocks, 128, 0, stream>>>(
        h1b, offsets, sorted_src, bfW2, b2, out, N);
}